// Round 1
// baseline (370.691 us; speedup 1.0000x reference)
//
#include <hip/hip_runtime.h>
#include <stdint.h>

#define B_SZ   32768
#define F_SZ   512
#define G_SZ   16
#define L_SZ   64
#define N_COLS 1024   // G*L
#define C_SZ   1000
#define M_TILE 64
#define A_STRIDE 520   // ushorts per LDS A row (pad: 512+8, keeps 16B alignment)
#define W_STRIDE 1040  // floats per LDS weighted row (pad: bank offset 16/row)

typedef __attribute__((ext_vector_type(8))) short short8;
typedef __attribute__((ext_vector_type(4))) float floatx4;

__device__ __forceinline__ unsigned short f2bf(float f) {
    unsigned int x = __float_as_uint(f);
    x += 0x7fffu + ((x >> 16) & 1u);   // RNE to bf16
    return (unsigned short)(x >> 16);
}

// ---- kernel 1: W f32 -> bf16 (1 MiB, stays L2-resident for the main GEMM) ----
__global__ __launch_bounds__(256) void convert_w_kernel(const float* __restrict__ W,
                                                        unsigned short* __restrict__ Wb) {
    int i = blockIdx.x * 256 + threadIdx.x;          // float4 index, 131072 total
    const float4* W4 = (const float4*)W;
    float4 v = W4[i];
    ushort4 u = make_ushort4(f2bf(v.x), f2bf(v.y), f2bf(v.z), f2bf(v.w));
    ((ushort4*)Wb)[i] = u;
}

// ---- kernel 2: invert label_ids into CSR (class -> list of columns) ----
__global__ __launch_bounds__(1024) void build_csr_kernel(const int* __restrict__ label_ids,
                                                         int* __restrict__ off,
                                                         int* __restrict__ list) {
    __shared__ int cnt[C_SZ];
    __shared__ int offs[C_SZ + 1];
    int t = threadIdx.x;                 // 0..1023 == column index g*64+l
    if (t < C_SZ) cnt[t] = 0;
    __syncthreads();
    int lbl = label_ids[t];
    atomicAdd(&cnt[lbl], 1);
    __syncthreads();
    if (t == 0) {
        int s = 0;
        for (int c = 0; c < C_SZ; ++c) { offs[c] = s; s += cnt[c]; }
        offs[C_SZ] = s;
    }
    __syncthreads();
    if (t < C_SZ) cnt[t] = offs[t];      // reuse as cursor
    __syncthreads();
    int pos = atomicAdd(&cnt[lbl], 1);
    list[pos] = t;
    if (t <= C_SZ) off[t] = offs[t];
}

// ---- kernel 3: fused GEMM (bf16 MFMA) + weighting + CSR gather ----
// Block: 1024 threads = 16 waves. Tile: 64 rows x ALL 1024 cols. K=512.
// Wave w owns cols [w*64, w*64+64): 4 col-tiles of 16. All waves cover 4 row-tiles.
__global__ __launch_bounds__(1024, 4) void mhc_main_kernel(
        const float* __restrict__ feat,            // [B][512] f32
        const float* __restrict__ gp,              // [B][16]  f32
        const unsigned short* __restrict__ Wb,     // [1024][512] bf16 (N x K = B-frag layout)
        const float* __restrict__ bias,            // [1024] f32 (g*64+l)
        const int* __restrict__ off,               // [1001]
        const int* __restrict__ list,              // [1024]
        float* __restrict__ out)                   // [B][1000] f32
{
    __shared__ __align__(16) char smem[66560];     // A-stage (64x520 bf16) aliased with weighted (16x1040 f32)
    __shared__ float gp_s[M_TILE * G_SZ];          // 64 rows x 16 groups
    __shared__ float bias_s[N_COLS];

    unsigned short* As = (unsigned short*)smem;
    float* WL = (float*)smem;

    const int t    = threadIdx.x;
    const int wave = t >> 6;          // 0..15
    const int lane = t & 63;
    const int m16  = lane & 15;
    const int quad = lane >> 4;       // 0..3
    const int r0   = blockIdx.x * M_TILE;

    // stage group_probs tile + bias (t = row*16+g and t = col respectively)
    gp_s[t]   = gp[r0 * G_SZ + t];
    bias_s[t] = bias[t];

    // stage A: 64 rows x 512 f32 -> bf16 LDS, coalesced float4 reads
    {
        const float4* f4 = (const float4*)(feat + (size_t)r0 * F_SZ);
        #pragma unroll
        for (int i = 0; i < 8; ++i) {
            int idx = t + i * 1024;            // 0..8191 ; row = idx/128, c4 = idx%128
            int row = idx >> 7;
            int c4  = idx & 127;
            float4 v = f4[idx];
            ushort4 u = make_ushort4(f2bf(v.x), f2bf(v.y), f2bf(v.z), f2bf(v.w));
            *(ushort4*)(As + row * A_STRIDE + c4 * 4) = u;
        }
    }
    __syncthreads();

    const floatx4 zero = {0.f, 0.f, 0.f, 0.f};
    floatx4 acc[4][4];
    #pragma unroll
    for (int i = 0; i < 4; ++i)
        #pragma unroll
        for (int j = 0; j < 4; ++j) acc[i][j] = zero;

    // fragment base pointers
    const unsigned short* aBase = As + m16 * A_STRIDE + quad * 8;
    const unsigned short* bBase = Wb + (size_t)(wave * 64 + m16) * F_SZ + quad * 8;

    #pragma unroll 4
    for (int kt = 0; kt < 16; ++kt) {             // K step = 32
        short8 a[4];
        #pragma unroll
        for (int rt = 0; rt < 4; ++rt)
            a[rt] = *(const short8*)(aBase + rt * 16 * A_STRIDE + kt * 32);
        #pragma unroll
        for (int ct = 0; ct < 4; ++ct) {
            short8 b = *(const short8*)(bBase + ct * 16 * F_SZ + kt * 32);
            #pragma unroll
            for (int rt = 0; rt < 4; ++rt)
                acc[rt][ct] = __builtin_amdgcn_mfma_f32_16x16x32_bf16(a[rt], b, acc[rt][ct], 0, 0, 0);
        }
    }

    // epilogue: 4 passes of 16 rows. weighted -> LDS, then CSR gather -> out.
    #pragma unroll 1
    for (int p = 0; p < 4; ++p) {
        __syncthreads();   // pass 0: also guards A-LDS alias; later: guards prior gather reads
        #pragma unroll
        for (int ct = 0; ct < 4; ++ct) {
            int col = wave * 64 + ct * 16 + m16;
            int g   = col >> 6;
            float bi = bias_s[col];
            #pragma unroll
            for (int r = 0; r < 4; ++r) {
                int rl = quad * 4 + r;                           // local row 0..15 (C/D layout)
                float v = gp_s[(p * 16 + rl) * G_SZ + g] * (acc[p][ct][r] + bi);
                WL[rl * W_STRIDE + col] = v;
            }
        }
        __syncthreads();
        for (int idx = t; idx < 16 * C_SZ; idx += 1024) {
            int rr = idx / C_SZ;
            int c  = idx - rr * C_SZ;
            int e0 = off[c], e1 = off[c + 1];
            float s = 0.f;
            for (int j = e0; j < e1; ++j) s += WL[rr * W_STRIDE + list[j]];
            out[(size_t)(r0 + p * 16 + rr) * C_SZ + c] = s;
        }
    }
}

extern "C" void kernel_launch(void* const* d_in, const int* in_sizes, int n_in,
                              void* d_out, int out_size, void* d_ws, size_t ws_size,
                              hipStream_t stream) {
    const float* feat  = (const float*)d_in[0];
    const float* gp    = (const float*)d_in[1];
    const float* W     = (const float*)d_in[2];
    const float* bias  = (const float*)d_in[3];
    const int* labels  = (const int*)d_in[4];
    float* out = (float*)d_out;

    unsigned short* Wb = (unsigned short*)d_ws;          // 1 MiB bf16 W
    int* off  = (int*)((char*)d_ws + (1 << 20));         // 1001 ints
    int* list = off + 1024;                              // 1024 ints

    convert_w_kernel<<<(G_SZ * L_SZ * F_SZ / 4) / 256, 256, 0, stream>>>(W, Wb);
    build_csr_kernel<<<1, 1024, 0, stream>>>(labels, off, list);
    mhc_main_kernel<<<B_SZ / M_TILE, 1024, 0, stream>>>(feat, gp, Wb, bias, off, list, out);
}

// Round 2
// 296.718 us; speedup vs baseline: 1.2493x; 1.2493x over previous
//
#include <hip/hip_runtime.h>
#include <stdint.h>

#define B_SZ   32768
#define F_SZ   512
#define G_SZ   16
#define L_SZ   64
#define N_COLS 1024   // G*L
#define C_SZ   1000
#define M_TILE 64
#define A_STRIDE 520    // ushorts per LDS A row (512+8; keeps 16B alignment, breaks pow2 stride)
#define W_STRIDE 1042   // floats per LDS weighted row (1042 % 8 == 2 -> quads spread over banks 0/8/16/24)
#define SMEM_BYTES 66688  // max(64*520*2 = 66560, 16*1042*4 = 66688)

typedef __attribute__((ext_vector_type(8))) short short8;
typedef __attribute__((ext_vector_type(4))) float floatx4;

__device__ __forceinline__ unsigned short f2bf(float f) {
    unsigned int x = __float_as_uint(f);
    x += 0x7fffu + ((x >> 16) & 1u);   // RNE to bf16
    return (unsigned short)(x >> 16);
}

// ---- kernel 1: invert label_ids into CSR with a parallel scan; emit the column
//      permutation (list), permuted bias, and per-slot group id ----
__global__ __launch_bounds__(1024) void build_csr_kernel(const int* __restrict__ label_ids,
                                                         const float* __restrict__ bias,
                                                         int* __restrict__ off,
                                                         int* __restrict__ list,
                                                         float* __restrict__ bias_p,
                                                         unsigned char* __restrict__ g_perm) {
    __shared__ int cnt[1024];   // counts -> inclusive scan (classes padded to 1024)
    __shared__ int cur[1024];   // scatter cursors
    const int t = threadIdx.x;            // 0..1023 == column index g*64+l
    cnt[t] = 0;
    __syncthreads();
    const int lbl = label_ids[t];
    atomicAdd(&cnt[lbl], 1);
    __syncthreads();
    // Hillis-Steele inclusive scan over 1024 entries
    int v = cnt[t];
    #pragma unroll
    for (int d = 1; d < 1024; d <<= 1) {
        int u = (t >= d) ? cnt[t - d] : 0;
        __syncthreads();
        v += u;
        cnt[t] = v;
        __syncthreads();
    }
    // exclusive offset for this thread's class slot
    int ex = (t == 0) ? 0 : cnt[t - 1];
    cur[t] = ex;
    if (t <= C_SZ) off[t] = (t == 0) ? 0 : cnt[t - 1];   // off[1000] == 1024
    __syncthreads();
    int pos = atomicAdd(&cur[lbl], 1);
    list[pos]   = t;
    bias_p[pos] = bias[t];
    g_perm[pos] = (unsigned char)(t >> 6);
}

// ---- kernel 2: W f32 -> bf16, rows permuted into CSR-list order ----
__global__ __launch_bounds__(256) void convert_w_kernel(const float* __restrict__ W,
                                                        const int* __restrict__ list,
                                                        unsigned short* __restrict__ Wb) {
    int idx = blockIdx.x * 256 + threadIdx.x;        // float4 index, 131072 total
    int row = idx >> 7;                              // output row j
    int c4  = idx & 127;
    int src = list[row];                             // original column
    const float4* W4 = (const float4*)W;
    float4 v = W4[src * 128 + c4];
    ushort4 u = make_ushort4(f2bf(v.x), f2bf(v.y), f2bf(v.z), f2bf(v.w));
    ((ushort4*)Wb)[idx] = u;
}

// ---- kernel 3: fused GEMM (bf16 MFMA) + weighting + contiguous-run gather ----
// Block: 1024 threads = 16 waves. Tile: 64 rows x ALL 1024 (permuted) cols. K=512.
__global__ __launch_bounds__(1024, 4) void mhc_main_kernel(
        const float* __restrict__ feat,            // [B][512] f32
        const float* __restrict__ gp,              // [B][16]  f32
        const unsigned short* __restrict__ Wb,     // [1024][512] bf16, permuted rows
        const float* __restrict__ bias_p,          // [1024] f32, permuted
        const int* __restrict__ off,               // [1001]
        const unsigned char* __restrict__ g_perm,  // [1024] group of each permuted col
        float* __restrict__ out)                   // [B][1000] f32
{
    __shared__ __align__(16) char smem[SMEM_BYTES]; // A-stage aliased with weighted tile
    __shared__ float gp_s[M_TILE * G_SZ];           // 64 rows x 16 groups
    __shared__ float bias_s[N_COLS];
    __shared__ unsigned char g_s[N_COLS];

    unsigned short* As = (unsigned short*)smem;
    float* WL = (float*)smem;

    const int t    = threadIdx.x;
    const int wave = t >> 6;          // 0..15
    const int lane = t & 63;
    const int m16  = lane & 15;
    const int quad = lane >> 4;       // 0..3
    const int r0   = blockIdx.x * M_TILE;

    // stage group_probs tile + permuted bias + per-col group
    gp_s[t]   = gp[r0 * G_SZ + t];
    bias_s[t] = bias_p[t];
    g_s[t]    = g_perm[t];

    // this thread's contiguous gather run (pass-invariant, lives in registers)
    int e0 = 0, e1 = 0;
    if (t < C_SZ) { e0 = off[t]; e1 = off[t + 1]; }

    // stage A: 64 rows x 512 f32 -> bf16 LDS, coalesced float4 reads
    {
        const float4* f4 = (const float4*)(feat + (size_t)r0 * F_SZ);
        #pragma unroll
        for (int i = 0; i < 8; ++i) {
            int idx = t + i * 1024;            // row = idx/128, c4 = idx%128
            int row = idx >> 7;
            int c4  = idx & 127;
            float4 v = f4[idx];
            ushort4 u = make_ushort4(f2bf(v.x), f2bf(v.y), f2bf(v.z), f2bf(v.w));
            *(ushort4*)(As + row * A_STRIDE + c4 * 4) = u;
        }
    }
    __syncthreads();

    const floatx4 zero = {0.f, 0.f, 0.f, 0.f};
    floatx4 acc[4][4];
    #pragma unroll
    for (int i = 0; i < 4; ++i)
        #pragma unroll
        for (int j = 0; j < 4; ++j) acc[i][j] = zero;

    const unsigned short* aBase = As + m16 * A_STRIDE + quad * 8;
    const unsigned short* bBase = Wb + (size_t)(wave * 64 + m16) * F_SZ + quad * 8;

    #pragma unroll 4
    for (int kt = 0; kt < 16; ++kt) {             // K step = 32
        short8 a[4];
        #pragma unroll
        for (int rt = 0; rt < 4; ++rt)
            a[rt] = *(const short8*)(aBase + rt * 16 * A_STRIDE + kt * 32);
        #pragma unroll
        for (int ct = 0; ct < 4; ++ct) {
            short8 b = *(const short8*)(bBase + ct * 16 * F_SZ + kt * 32);
            #pragma unroll
            for (int rt = 0; rt < 4; ++rt)
                acc[rt][ct] = __builtin_amdgcn_mfma_f32_16x16x32_bf16(a[rt], b, acc[rt][ct], 0, 0, 0);
        }
    }

    // epilogue: 4 passes of 16 rows. weighted -> LDS, then contiguous-run gather -> out.
    #pragma unroll 1
    for (int p = 0; p < 4; ++p) {
        __syncthreads();   // pass 0: guards A-LDS alias; later: guards prior gather reads
        #pragma unroll
        for (int ct = 0; ct < 4; ++ct) {
            int col = wave * 64 + ct * 16 + m16;
            int g   = g_s[col];
            float bi = bias_s[col];
            #pragma unroll
            for (int r = 0; r < 4; ++r) {
                int rl = quad * 4 + r;                           // local row 0..15 (C/D layout)
                float v = gp_s[(p * 16 + rl) * G_SZ + g] * (acc[p][ct][r] + bi);
                WL[rl * W_STRIDE + col] = v;
            }
        }
        __syncthreads();
        if (t < C_SZ) {
            #pragma unroll
            for (int h = 0; h < 4; ++h) {                        // 4 rows per chunk
                float s0 = 0.f, s1 = 0.f, s2 = 0.f, s3 = 0.f;
                for (int j = e0; j < e1; ++j) {
                    s0 += WL[(h * 4 + 0) * W_STRIDE + j];
                    s1 += WL[(h * 4 + 1) * W_STRIDE + j];
                    s2 += WL[(h * 4 + 2) * W_STRIDE + j];
                    s3 += WL[(h * 4 + 3) * W_STRIDE + j];
                }
                size_t rowg = (size_t)(r0 + p * 16 + h * 4);
                out[(rowg + 0) * C_SZ + t] = s0;
                out[(rowg + 1) * C_SZ + t] = s1;
                out[(rowg + 2) * C_SZ + t] = s2;
                out[(rowg + 3) * C_SZ + t] = s3;
            }
        }
    }
}

extern "C" void kernel_launch(void* const* d_in, const int* in_sizes, int n_in,
                              void* d_out, int out_size, void* d_ws, size_t ws_size,
                              hipStream_t stream) {
    const float* feat  = (const float*)d_in[0];
    const float* gp    = (const float*)d_in[1];
    const float* W     = (const float*)d_in[2];
    const float* bias  = (const float*)d_in[3];
    const int* labels  = (const int*)d_in[4];
    float* out = (float*)d_out;

    unsigned short* Wb = (unsigned short*)d_ws;                    // 1 MiB bf16 W (permuted)
    char* base = (char*)d_ws + (1 << 20);
    int* off             = (int*)base;                             // 1001 ints (pad 4 KB)
    int* list            = (int*)(base + 4096);                    // 1024 ints
    float* bias_p        = (float*)(base + 8192);                  // 1024 f32
    unsigned char* g_prm = (unsigned char*)(base + 12288);         // 1024 bytes

    build_csr_kernel<<<1, 1024, 0, stream>>>(labels, bias, off, list, bias_p, g_prm);
    convert_w_kernel<<<(N_COLS * F_SZ / 4) / 256, 256, 0, stream>>>(W, list, Wb);
    mhc_main_kernel<<<B_SZ / M_TILE, 1024, 0, stream>>>(feat, gp, Wb, bias_p, off, g_prm, out);
}

// Round 3
// 256.208 us; speedup vs baseline: 1.4468x; 1.1581x over previous
//
#include <hip/hip_runtime.h>
#include <stdint.h>

#define B_SZ   32768
#define F_SZ   512
#define G_SZ   16
#define L_SZ   64
#define N_COLS 1024   // G*L
#define C_SZ   1000
#define M_TILE 64
#define A_STRIDE 520    // ushorts per LDS A row (512+8; keeps 16B alignment, breaks pow2 stride)
#define W_STRIDE 1042   // floats per LDS weighted row (1042 % 8 == 2 -> quads spread over banks 0/8/16/24)
#define SMEM_BYTES 66688  // max(64*520*2 = 66560, 16*1042*4 = 66688)

typedef __attribute__((ext_vector_type(8))) short short8;
typedef __attribute__((ext_vector_type(4))) float floatx4;

__device__ __forceinline__ unsigned short f2bf(float f) {
    unsigned int x = __float_as_uint(f);
    x += 0x7fffu + ((x >> 16) & 1u);   // RNE to bf16
    return (unsigned short)(x >> 16);
}

// ---- kernel 1: invert label_ids into CSR with a parallel scan; emit the column
//      permutation (list), permuted bias, and per-slot group id ----
__global__ __launch_bounds__(1024) void build_csr_kernel(const int* __restrict__ label_ids,
                                                         const float* __restrict__ bias,
                                                         int* __restrict__ off,
                                                         int* __restrict__ list,
                                                         float* __restrict__ bias_p,
                                                         unsigned char* __restrict__ g_perm) {
    __shared__ int cnt[1024];   // counts -> inclusive scan (classes padded to 1024)
    __shared__ int cur[1024];   // scatter cursors
    const int t = threadIdx.x;            // 0..1023 == column index g*64+l
    cnt[t] = 0;
    __syncthreads();
    const int lbl = label_ids[t];
    atomicAdd(&cnt[lbl], 1);
    __syncthreads();
    // Hillis-Steele inclusive scan over 1024 entries
    int v = cnt[t];
    #pragma unroll
    for (int d = 1; d < 1024; d <<= 1) {
        int u = (t >= d) ? cnt[t - d] : 0;
        __syncthreads();
        v += u;
        cnt[t] = v;
        __syncthreads();
    }
    // exclusive offset for this thread's class slot
    int ex = (t == 0) ? 0 : cnt[t - 1];
    cur[t] = ex;
    if (t <= C_SZ) off[t] = (t == 0) ? 0 : cnt[t - 1];   // off[1000] == 1024
    __syncthreads();
    int pos = atomicAdd(&cur[lbl], 1);
    list[pos]   = t;
    bias_p[pos] = bias[t];
    g_perm[pos] = (unsigned char)(t >> 6);
}

// ---- kernel 2: W f32 -> bf16, rows permuted into CSR-list order ----
__global__ __launch_bounds__(256) void convert_w_kernel(const float* __restrict__ W,
                                                        const int* __restrict__ list,
                                                        unsigned short* __restrict__ Wb) {
    int idx = blockIdx.x * 256 + threadIdx.x;        // float4 index, 131072 total
    int row = idx >> 7;                              // output row j
    int c4  = idx & 127;
    int src = list[row];                             // original column
    const float4* W4 = (const float4*)W;
    float4 v = W4[src * 128 + c4];
    ushort4 u = make_ushort4(f2bf(v.x), f2bf(v.y), f2bf(v.z), f2bf(v.w));
    ((ushort4*)Wb)[idx] = u;
}

// ---- kernel 3: fused GEMM (bf16 MFMA) + weighting + contiguous-run gather ----
// Block: 1024 threads = 16 waves. Tile: 64 rows x ALL 1024 (permuted) cols. K=512.
__global__ __launch_bounds__(1024, 4) void mhc_main_kernel(
        const float* __restrict__ feat,            // [B][512] f32
        const float* __restrict__ gp,              // [B][16]  f32
        const unsigned short* __restrict__ Wb,     // [1024][512] bf16, permuted rows
        const float* __restrict__ bias_p,          // [1024] f32, permuted
        const int* __restrict__ off,               // [1001]
        const unsigned char* __restrict__ g_perm,  // [1024] group of each permuted col
        float* __restrict__ out)                   // [B][1000] f32
{
    __shared__ __align__(16) char smem[SMEM_BYTES]; // A-stage aliased with weighted tile
    __shared__ float gp_s[M_TILE * G_SZ];           // 64 rows x 16 groups
    __shared__ float bias_s[N_COLS];
    __shared__ unsigned char g_s[N_COLS];

    unsigned short* As = (unsigned short*)smem;
    float* WL = (float*)smem;

    const int t    = threadIdx.x;
    const int wave = t >> 6;          // 0..15
    const int lane = t & 63;
    const int m16  = lane & 15;
    const int quad = lane >> 4;       // 0..3
    const int r0   = blockIdx.x * M_TILE;

    // stage group_probs tile + permuted bias + per-col group
    gp_s[t]   = gp[r0 * G_SZ + t];
    bias_s[t] = bias_p[t];
    g_s[t]    = g_perm[t];

    // this thread's contiguous gather run (pass-invariant, lives in registers)
    int e0 = 0, e1 = 0;
    if (t < C_SZ) { e0 = off[t]; e1 = off[t + 1]; }

    // stage A: 64 rows x 512 f32 -> bf16 LDS, coalesced float4 reads
    {
        const float4* f4 = (const float4*)(feat + (size_t)r0 * F_SZ);
        #pragma unroll
        for (int i = 0; i < 8; ++i) {
            int idx = t + i * 1024;            // row = idx/128, c4 = idx%128
            int row = idx >> 7;
            int c4  = idx & 127;
            float4 v = f4[idx];
            ushort4 u = make_ushort4(f2bf(v.x), f2bf(v.y), f2bf(v.z), f2bf(v.w));
            *(ushort4*)(As + row * A_STRIDE + c4 * 4) = u;
        }
    }
    __syncthreads();

    const floatx4 zero = {0.f, 0.f, 0.f, 0.f};
    floatx4 acc[4][4];
    #pragma unroll
    for (int i = 0; i < 4; ++i)
        #pragma unroll
        for (int j = 0; j < 4; ++j) acc[i][j] = zero;

    const unsigned short* aBase = As + m16 * A_STRIDE + quad * 8;
    const unsigned short* bBase = Wb + (size_t)(wave * 64 + m16) * F_SZ + quad * 8;

    #pragma unroll 4
    for (int kt = 0; kt < 16; ++kt) {             // K step = 32
        short8 a[4];
        #pragma unroll
        for (int rt = 0; rt < 4; ++rt)
            a[rt] = *(const short8*)(aBase + rt * 16 * A_STRIDE + kt * 32);
        #pragma unroll
        for (int ct = 0; ct < 4; ++ct) {
            short8 b = *(const short8*)(bBase + ct * 16 * F_SZ + kt * 32);
            #pragma unroll
            for (int rt = 0; rt < 4; ++rt)
                acc[rt][ct] = __builtin_amdgcn_mfma_f32_16x16x32_bf16(a[rt], b, acc[rt][ct], 0, 0, 0);
        }
    }

    // epilogue: 4 passes of 16 rows. weighted -> LDS, then contiguous-run gather -> out.
    // FULLY UNROLLED so acc[p][...] indexing is static — dynamic p spilled the whole
    // accumulator to scratch (measured: +128 MB WRITE_SIZE, round 2).
    #pragma unroll
    for (int p = 0; p < 4; ++p) {
        __syncthreads();   // pass 0: guards A-LDS alias; later: guards prior gather reads
        #pragma unroll
        for (int ct = 0; ct < 4; ++ct) {
            int col = wave * 64 + ct * 16 + m16;
            int g   = g_s[col];
            float bi = bias_s[col];
            #pragma unroll
            for (int r = 0; r < 4; ++r) {
                int rl = quad * 4 + r;                           // local row 0..15 (C/D layout)
                float v = gp_s[(p * 16 + rl) * G_SZ + g] * (acc[p][ct][r] + bi);
                WL[rl * W_STRIDE + col] = v;
            }
        }
        __syncthreads();
        if (t < C_SZ) {
            #pragma unroll
            for (int h = 0; h < 4; ++h) {                        // 4 rows per chunk
                float s0 = 0.f, s1 = 0.f, s2 = 0.f, s3 = 0.f;
                for (int j = e0; j < e1; ++j) {
                    s0 += WL[(h * 4 + 0) * W_STRIDE + j];
                    s1 += WL[(h * 4 + 1) * W_STRIDE + j];
                    s2 += WL[(h * 4 + 2) * W_STRIDE + j];
                    s3 += WL[(h * 4 + 3) * W_STRIDE + j];
                }
                size_t rowg = (size_t)(r0 + p * 16 + h * 4);
                out[(rowg + 0) * C_SZ + t] = s0;
                out[(rowg + 1) * C_SZ + t] = s1;
                out[(rowg + 2) * C_SZ + t] = s2;
                out[(rowg + 3) * C_SZ + t] = s3;
            }
        }
    }
}

extern "C" void kernel_launch(void* const* d_in, const int* in_sizes, int n_in,
                              void* d_out, int out_size, void* d_ws, size_t ws_size,
                              hipStream_t stream) {
    const float* feat  = (const float*)d_in[0];
    const float* gp    = (const float*)d_in[1];
    const float* W     = (const float*)d_in[2];
    const float* bias  = (const float*)d_in[3];
    const int* labels  = (const int*)d_in[4];
    float* out = (float*)d_out;

    unsigned short* Wb = (unsigned short*)d_ws;                    // 1 MiB bf16 W (permuted)
    char* base = (char*)d_ws + (1 << 20);
    int* off             = (int*)base;                             // 1001 ints (pad 4 KB)
    int* list            = (int*)(base + 4096);                    // 1024 ints
    float* bias_p        = (float*)(base + 8192);                  // 1024 f32
    unsigned char* g_prm = (unsigned char*)(base + 12288);         // 1024 bytes

    build_csr_kernel<<<1, 1024, 0, stream>>>(labels, bias, off, list, bias_p, g_prm);
    convert_w_kernel<<<(N_COLS * F_SZ / 4) / 256, 256, 0, stream>>>(W, list, Wb);
    mhc_main_kernel<<<B_SZ / M_TILE, 1024, 0, stream>>>(feat, gp, Wb, bias_p, off, g_prm, out);
}